// Round 13
// baseline (373.912 us; speedup 1.0000x reference)
//
#include <hip/hip_runtime.h>

typedef float  f32x4  __attribute__((ext_vector_type(4)));
typedef __bf16 bf16x8 __attribute__((ext_vector_type(8)));
typedef __bf16 bf16x4 __attribute__((ext_vector_type(4)));

// ---------- async global->LDS, 16B per lane ----------
__device__ __forceinline__ void gl_lds16(const void* g, void* l) {
    __builtin_amdgcn_global_load_lds(
        (const __attribute__((address_space(1))) void*)g,
        (__attribute__((address_space(3))) void*)l, 16, 0, 0);
}

// bijective XCD-aware remap (m204)
__device__ __forceinline__ int xcd_swz(int wg, int nwg) {
    int xcd = wg & 7, idx = wg >> 3;
    int q = nwg >> 3, r = nwg & 7;
    return (xcd < r ? xcd * (q + 1) : r * (q + 1) + (xcd - r) * q) + idx;
}

// ---------- split f32 -> bf16 hi + bf16 lo ----------
__global__ void split_f32(const float* __restrict__ in, __bf16* __restrict__ hi,
                          __bf16* __restrict__ lo, long n) {
    long i = ((long)blockIdx.x * blockDim.x + threadIdx.x) * 4;
    if (i >= n) return;
    float4 v = *(const float4*)&in[i];
    bf16x4 h, l;
    h[0] = (__bf16)v.x; l[0] = (__bf16)(v.x - (float)h[0]);
    h[1] = (__bf16)v.y; l[1] = (__bf16)(v.y - (float)h[1]);
    h[2] = (__bf16)v.z; l[2] = (__bf16)(v.z - (float)h[2]);
    h[3] = (__bf16)v.w; l[3] = (__bf16)(v.w - (float)h[3]);
    *(bf16x4*)&hi[i] = h;
    *(bf16x4*)&lo[i] = l;
}

// ---------- fused double split: blocks [0,half) handle A, [half,2*half) handle B ----------
__global__ void split2_f32(const float* __restrict__ a, const float* __restrict__ b,
                           __bf16* __restrict__ ah, __bf16* __restrict__ al,
                           __bf16* __restrict__ bh, __bf16* __restrict__ bl, long n) {
    long i = ((long)blockIdx.x * blockDim.x + threadIdx.x) * 4;
    const float* src = a;
    __bf16 *dh = ah, *dl = al;
    if (i >= n) { i -= n; src = b; dh = bh; dl = bl; }
    if (i >= n) return;
    float4 v = *(const float4*)&src[i];
    bf16x4 h, l;
    h[0] = (__bf16)v.x; l[0] = (__bf16)(v.x - (float)h[0]);
    h[1] = (__bf16)v.y; l[1] = (__bf16)(v.y - (float)h[1]);
    h[2] = (__bf16)v.z; l[2] = (__bf16)(v.z - (float)h[2]);
    h[3] = (__bf16)v.w; l[3] = (__bf16)(v.w - (float)h[3]);
    *(bf16x4*)&dh[i] = h;
    *(bf16x4*)&dl[i] = l;
}

// ---------- f32 -> f32 copy (full, unconditional) ----------
__global__ void copy_f32(const float* __restrict__ in, float* __restrict__ out) {
    long i = ((long)blockIdx.x * blockDim.x + threadIdx.x) * 4;
    *(float4*)&out[i] = *(const float4*)&in[i];
}

// Wb [256][64] f32 -> Wbt [64][256] bf16
__global__ void cvt_wb(const float* __restrict__ Wb, __bf16* __restrict__ Wbt) {
    int idx = blockIdx.x * 256 + threadIdx.x;
    int k = idx >> 6, n = idx & 63;
    Wbt[n * 256 + k] = (__bf16)Wb[idx];
}

// ---------- WvbT[j*64+d][k] = sum_e Wv[k][j*256+e] * Wbt[d][e]  (reads f32 Wv directly) ----------
__global__ __launch_bounds__(256) void wvb_kernel(const float* __restrict__ Wv,
                                                  const __bf16* __restrict__ Wbt,
                                                  __bf16* __restrict__ WvbT) {
    const int kb = blockIdx.x;   // 0..24
    const int j  = blockIdx.y;   // 0..24
    const int tid = threadIdx.x;
    const int w = tid >> 6, l = tid & 63;
    const long r0 = (long)kb * 64 + w * 16;
    const int lr = l & 15, lk8 = (l >> 4) * 8;
    f32x4 acc[4];
    #pragma unroll
    for (int n = 0; n < 4; ++n) acc[n] = (f32x4){0.f, 0.f, 0.f, 0.f};
    #pragma unroll
    for (int kt = 0; kt < 8; ++kt) {
        const int k = kt * 32 + lk8;
        const float* ap = &Wv[(r0 + lr) * 6400 + j * 256 + k];
        float4 f0 = *(const float4*)ap;
        float4 f1 = *(const float4*)(ap + 4);
        bf16x8 a = {(__bf16)f0.x, (__bf16)f0.y, (__bf16)f0.z, (__bf16)f0.w,
                    (__bf16)f1.x, (__bf16)f1.y, (__bf16)f1.z, (__bf16)f1.w};
        #pragma unroll
        for (int n = 0; n < 4; ++n) {
            bf16x8 b = *(const bf16x8*)&Wbt[(n * 16 + lr) * 256 + k];
            acc[n] = __builtin_amdgcn_mfma_f32_16x16x32_bf16(a, b, acc[n], 0, 0, 0);
        }
    }
    const int rr = (l >> 4) * 4;
    #pragma unroll
    for (int n = 0; n < 4; ++n)
        #pragma unroll
        for (int r = 0; r < 4; ++r)
            WvbT[(long)(j * 64 + n * 16 + lr) * 1600 + r0 + rr + r] = (__bf16)acc[n][r];
}

// ---------- 256^2 fused split-precision GEMM (single-buffer, 8 waves, 8x4 frags) ----------
// LDS-BW-bound optimization: wave tile 128x64 -> 24 ds_reads per 96 MFMA
// (vs 16 per 48 at 64x64) + stage writes amortized 4x. 128 KB LDS, 1 block/CU,
// 2 waves/SIMD. f32 atomic epilogue (K-split), row/col masked.
template <bool SWZ>
__global__ __launch_bounds__(512, 2) void gemm3w(
    const __bf16* __restrict__ Ahi, const __bf16* __restrict__ Alo,
    const __bf16* __restrict__ Bhi, const __bf16* __restrict__ Blo,
    float* __restrict__ C,
    int ktot, int nkc, int lda, int ldb, int ldc, int M, int N, float scale)
{
    __shared__ __bf16 AsH[16384], AsL[16384], BsH[16384], BsL[16384];  // 128 KB
    int bx = blockIdx.x, by = blockIdx.y;
    if (SWZ) {
        int f = xcd_swz(by * gridDim.x + bx, gridDim.x * gridDim.y);
        bx = f % gridDim.x; by = f / gridDim.x;
    }
    const int n0 = bx * 256, m0 = by * 256;
    const int kc = blockIdx.z;
    const int kbeg = (kc * ktot) / nkc;
    const int kend = ((kc + 1) * ktot) / nkc;

    const int tid = threadIdx.x;
    const int w = tid >> 6, l = tid & 63;
    const int wm = w >> 2, wn = w & 3;           // 2M x 4N waves; wave tile 128x64
    const int lr = l & 15;
    const int lk8 = (l >> 4) * 8;
    const int kswz = (lr & 7) << 3;
    const int srow = l >> 3;
    const int scol = ((l & 7) ^ (l >> 3)) * 8;   // pre-swizzled source col

    f32x4 acc[8][4];
    #pragma unroll
    for (int mf = 0; mf < 8; ++mf)
        #pragma unroll
        for (int nf = 0; nf < 4; ++nf) acc[mf][nf] = (f32x4){0.f, 0.f, 0.f, 0.f};

    for (int kt = kbeg; kt < kend; ++kt) {
        const int k0 = kt << 6;
        __syncthreads();
        #pragma unroll
        for (int it = 0; it < 4; ++it) {
            const int j = it * 8 + w;            // chunk 0..31 (8 rows each)
            const int grow = j * 8 + srow;       // 0..255
            const long ga = (long)(m0 + grow) * lda + k0 + scol;
            const long gb = (long)(n0 + grow) * ldb + k0 + scol;
            gl_lds16(Ahi + ga, &AsH[j * 512]);
            gl_lds16(Alo + ga, &AsL[j * 512]);
            gl_lds16(Bhi + gb, &BsH[j * 512]);
            gl_lds16(Blo + gb, &BsL[j * 512]);
        }
        __syncthreads();
        #pragma unroll
        for (int kk = 0; kk < 2; ++kk) {
            const int kx = (kk * 32 + lk8) ^ kswz;
            bf16x8 ah[8], bh[4];
            #pragma unroll
            for (int mf = 0; mf < 8; ++mf)
                ah[mf] = *(const bf16x8*)&AsH[(wm * 128 + mf * 16 + lr) * 64 + kx];
            #pragma unroll
            for (int nf = 0; nf < 4; ++nf)
                bh[nf] = *(const bf16x8*)&BsH[(wn * 64 + nf * 16 + lr) * 64 + kx];
            #pragma unroll
            for (int mf = 0; mf < 8; ++mf)
                #pragma unroll
                for (int nf = 0; nf < 4; ++nf)
                    acc[mf][nf] = __builtin_amdgcn_mfma_f32_16x16x32_bf16(ah[mf], bh[nf], acc[mf][nf], 0, 0, 0);
            {   // pass 2: hi . lo
                bf16x8 bl[4];
                #pragma unroll
                for (int nf = 0; nf < 4; ++nf)
                    bl[nf] = *(const bf16x8*)&BsL[(wn * 64 + nf * 16 + lr) * 64 + kx];
                #pragma unroll
                for (int mf = 0; mf < 8; ++mf)
                    #pragma unroll
                    for (int nf = 0; nf < 4; ++nf)
                        acc[mf][nf] = __builtin_amdgcn_mfma_f32_16x16x32_bf16(ah[mf], bl[nf], acc[mf][nf], 0, 0, 0);
            }
            {   // pass 3: lo . hi
                #pragma unroll
                for (int mf = 0; mf < 8; ++mf) {
                    bf16x8 al = *(const bf16x8*)&AsL[(wm * 128 + mf * 16 + lr) * 64 + kx];
                    #pragma unroll
                    for (int nf = 0; nf < 4; ++nf)
                        acc[mf][nf] = __builtin_amdgcn_mfma_f32_16x16x32_bf16(al, bh[nf], acc[mf][nf], 0, 0, 0);
                }
            }
        }
    }

    const int rbase = m0 + wm * 128 + (l >> 4) * 4;
    const int cbase = n0 + wn * 64 + lr;
    #pragma unroll
    for (int mf = 0; mf < 8; ++mf)
        #pragma unroll
        for (int nf = 0; nf < 4; ++nf)
            #pragma unroll
            for (int r = 0; r < 4; ++r) {
                int row = rbase + mf * 16 + r;
                int col = cbase + nf * 16;
                if (row < M && col < N)
                    unsafeAtomicAdd(&C[(long)row * ldc + col], acc[mf][nf][r] * scale);
            }
}

// ---------- fused split-precision GEMM, 128^2 (s-GEMM) ----------
// OUTMODE: 0 = f32 store, 1 = f32 atomic-accumulate, 2 = bf16 hi/lo split store
template <int OUTMODE, bool CAUSAL, bool SWZ>
__global__ __launch_bounds__(256) void gemm3f(
    const __bf16* __restrict__ Ahi, const __bf16* __restrict__ Alo,
    const __bf16* __restrict__ Bhi, const __bf16* __restrict__ Blo,
    float* __restrict__ C, __bf16* __restrict__ Ch, __bf16* __restrict__ Cl,
    int ktot, int nkc, int lda, int ldb, int ldc, int M, int N,
    long sA, long sB, long sC, float scale)
{
    __shared__ __bf16 AsH[8192], AsL[8192], BsH[8192], BsL[8192];  // 64 KB
    int bx = blockIdx.x, by = blockIdx.y;
    if (SWZ) {
        int f = xcd_swz(by * gridDim.x + bx, gridDim.x * gridDim.y);
        bx = f % gridDim.x; by = f / gridDim.x;
    }
    const int n0 = bx * 128, m0 = by * 128;
    if (CAUSAL && n0 > m0) return;
    const int bz = blockIdx.z;
    const int batch = bz / nkc, kc = bz % nkc;
    Ahi += (long)batch * sA; Alo += (long)batch * sA;
    Bhi += (long)batch * sB; Blo += (long)batch * sB;
    const int kbeg = (kc * ktot) / nkc;
    const int kend = ((kc + 1) * ktot) / nkc;

    const int tid = threadIdx.x;
    const int w = tid >> 6, l = tid & 63;
    const int wr = w >> 1, wc = w & 1;
    const int lr = l & 15;
    const int lk8 = (l >> 4) * 8;
    const int kswz = (lr & 7) << 3;
    const int srow = l >> 3;
    const int scol = ((l & 7) ^ (l >> 3)) * 8;

    f32x4 acc[4][4];
    #pragma unroll
    for (int m = 0; m < 4; ++m)
        #pragma unroll
        for (int n = 0; n < 4; ++n) acc[m][n] = (f32x4){0.f, 0.f, 0.f, 0.f};

    for (int kt = kbeg; kt < kend; ++kt) {
        const int k0 = kt << 6;
        __syncthreads();
        #pragma unroll
        for (int it = 0; it < 4; ++it) {
            const int j = it * 4 + w;
            const int grow = j * 8 + srow;
            const long ga = (long)(m0 + grow) * lda + k0 + scol;
            const long gb = (long)(n0 + grow) * ldb + k0 + scol;
            gl_lds16(Ahi + ga, &AsH[j * 512]);
            gl_lds16(Alo + ga, &AsL[j * 512]);
            gl_lds16(Bhi + gb, &BsH[j * 512]);
            gl_lds16(Blo + gb, &BsL[j * 512]);
        }
        __syncthreads();
        #pragma unroll
        for (int kk = 0; kk < 2; ++kk) {
            const int kx = (kk * 32 + lk8) ^ kswz;
            bf16x8 ah[4], bh[4], tt[4];
            #pragma unroll
            for (int m = 0; m < 4; ++m)
                ah[m] = *(const bf16x8*)&AsH[(wr * 64 + m * 16 + lr) * 64 + kx];
            #pragma unroll
            for (int n = 0; n < 4; ++n)
                bh[n] = *(const bf16x8*)&BsH[(wc * 64 + n * 16 + lr) * 64 + kx];
            #pragma unroll
            for (int m = 0; m < 4; ++m)
                #pragma unroll
                for (int n = 0; n < 4; ++n)
                    acc[m][n] = __builtin_amdgcn_mfma_f32_16x16x32_bf16(ah[m], bh[n], acc[m][n], 0, 0, 0);
            #pragma unroll
            for (int n = 0; n < 4; ++n)
                tt[n] = *(const bf16x8*)&BsL[(wc * 64 + n * 16 + lr) * 64 + kx];
            #pragma unroll
            for (int m = 0; m < 4; ++m)
                #pragma unroll
                for (int n = 0; n < 4; ++n)
                    acc[m][n] = __builtin_amdgcn_mfma_f32_16x16x32_bf16(ah[m], tt[n], acc[m][n], 0, 0, 0);
            #pragma unroll
            for (int m = 0; m < 4; ++m)
                tt[m] = *(const bf16x8*)&AsL[(wr * 64 + m * 16 + lr) * 64 + kx];
            #pragma unroll
            for (int m = 0; m < 4; ++m)
                #pragma unroll
                for (int n = 0; n < 4; ++n)
                    acc[m][n] = __builtin_amdgcn_mfma_f32_16x16x32_bf16(tt[m], bh[n], acc[m][n], 0, 0, 0);
        }
    }

    const int r0 = wr * 64 + (l >> 4) * 4;
    const int c0 = wc * 64 + lr;
    #pragma unroll
    for (int m = 0; m < 4; ++m)
        #pragma unroll
        for (int n = 0; n < 4; ++n)
            #pragma unroll
            for (int r = 0; r < 4; ++r) {
                int row = m0 + r0 + m * 16 + r;
                int col = n0 + c0 + n * 16;
                if (row < M && col < N) {
                    float v = acc[m][n][r] * scale;
                    long idx = (long)batch * sC + (long)row * ldc + col;
                    if (OUTMODE == 1) {
                        unsafeAtomicAdd(&C[idx], v);
                    } else if (OUTMODE == 2) {
                        __bf16 h = (__bf16)v;
                        Ch[idx] = h;
                        Cl[idx] = (__bf16)(v - (float)h);
                    } else {
                        C[idx] = v;
                    }
                }
            }
}

// ---------- fused t-GEMM + VW-GEMM, one dispatch (z=0: t 3-pass, z=1: VW 1-pass) ----------
template <bool SWZ>
__global__ __launch_bounds__(256) void gemm3m(
    const __bf16* __restrict__ Ahi, const __bf16* __restrict__ Alo,
    const __bf16* __restrict__ B1h, const __bf16* __restrict__ B1l,
    const __bf16* __restrict__ B2,
    __bf16* __restrict__ Ch, __bf16* __restrict__ Cl,
    __bf16* __restrict__ Cv)
{
    __shared__ __bf16 AsH[8192], AsL[8192], BsH[8192], BsL[8192];
    int bx = blockIdx.x, by = blockIdx.y;
    if (SWZ) {
        int f = xcd_swz(by * gridDim.x + bx, gridDim.x * gridDim.y);
        bx = f % gridDim.x; by = f / gridDim.x;
    }
    const int n0 = bx * 128, m0 = by * 128;
    const int tid = threadIdx.x;
    const int w = tid >> 6, l = tid & 63;
    const int wr = w >> 1, wc = w & 1;
    const int lr = l & 15;
    const int lk8 = (l >> 4) * 8;
    const int kswz = (lr & 7) << 3;
    const int srow = l >> 3;
    const int scol = ((l & 7) ^ (l >> 3)) * 8;

    f32x4 acc[4][4];
    #pragma unroll
    for (int m = 0; m < 4; ++m)
        #pragma unroll
        for (int n = 0; n < 4; ++n) acc[m][n] = (f32x4){0.f, 0.f, 0.f, 0.f};

    if (blockIdx.z == 0) {
        for (int kt = 0; kt < 25; ++kt) {
            const int k0 = kt << 6;
            __syncthreads();
            #pragma unroll
            for (int it = 0; it < 4; ++it) {
                const int j = it * 4 + w;
                const int grow = j * 8 + srow;
                const long ga = (long)(m0 + grow) * 1600 + k0 + scol;
                const long gb = (long)(n0 + grow) * 1600 + k0 + scol;
                gl_lds16(Ahi + ga, &AsH[j * 512]);
                gl_lds16(Alo + ga, &AsL[j * 512]);
                gl_lds16(B1h + gb, &BsH[j * 512]);
                gl_lds16(B1l + gb, &BsL[j * 512]);
            }
            __syncthreads();
            #pragma unroll
            for (int kk = 0; kk < 2; ++kk) {
                const int kx = (kk * 32 + lk8) ^ kswz;
                bf16x8 ah[4], bh[4], tt[4];
                #pragma unroll
                for (int m = 0; m < 4; ++m)
                    ah[m] = *(const bf16x8*)&AsH[(wr * 64 + m * 16 + lr) * 64 + kx];
                #pragma unroll
                for (int n = 0; n < 4; ++n)
                    bh[n] = *(const bf16x8*)&BsH[(wc * 64 + n * 16 + lr) * 64 + kx];
                #pragma unroll
                for (int m = 0; m < 4; ++m)
                    #pragma unroll
                    for (int n = 0; n < 4; ++n)
                        acc[m][n] = __builtin_amdgcn_mfma_f32_16x16x32_bf16(ah[m], bh[n], acc[m][n], 0, 0, 0);
                #pragma unroll
                for (int n = 0; n < 4; ++n)
                    tt[n] = *(const bf16x8*)&BsL[(wc * 64 + n * 16 + lr) * 64 + kx];
                #pragma unroll
                for (int m = 0; m < 4; ++m)
                    #pragma unroll
                    for (int n = 0; n < 4; ++n)
                        acc[m][n] = __builtin_amdgcn_mfma_f32_16x16x32_bf16(ah[m], tt[n], acc[m][n], 0, 0, 0);
                #pragma unroll
                for (int m = 0; m < 4; ++m)
                    tt[m] = *(const bf16x8*)&AsL[(wr * 64 + m * 16 + lr) * 64 + kx];
                #pragma unroll
                for (int m = 0; m < 4; ++m)
                    #pragma unroll
                    for (int n = 0; n < 4; ++n)
                        acc[m][n] = __builtin_amdgcn_mfma_f32_16x16x32_bf16(tt[m], bh[n], acc[m][n], 0, 0, 0);
            }
        }
        const int r0 = wr * 64 + (l >> 4) * 4;
        const int c0 = wc * 64 + lr;
        #pragma unroll
        for (int m = 0; m < 4; ++m)
            #pragma unroll
            for (int n = 0; n < 4; ++n)
                #pragma unroll
                for (int r = 0; r < 4; ++r) {
                    int row = m0 + r0 + m * 16 + r;
                    int col = n0 + c0 + n * 16;
                    if (col < 1600) {
                        float v = acc[m][n][r];
                        long idx = (long)row * 1600 + col;
                        __bf16 h = (__bf16)v;
                        Ch[idx] = h;
                        Cl[idx] = (__bf16)(v - (float)h);
                    }
                }
    } else {
        for (int kt = 0; kt < 25; ++kt) {
            const int k0 = kt << 6;
            __syncthreads();
            #pragma unroll
            for (int it = 0; it < 4; ++it) {
                const int j = it * 4 + w;
                const int grow = j * 8 + srow;
                gl_lds16(Ahi + (long)(m0 + grow) * 1600 + k0 + scol, &AsH[j * 512]);
                gl_lds16(B2  + (long)(n0 + grow) * 1600 + k0 + scol, &BsH[j * 512]);
            }
            __syncthreads();
            #pragma unroll
            for (int kk = 0; kk < 2; ++kk) {
                const int kx = (kk * 32 + lk8) ^ kswz;
                bf16x8 a[4], b[4];
                #pragma unroll
                for (int m = 0; m < 4; ++m)
                    a[m] = *(const bf16x8*)&AsH[(wr * 64 + m * 16 + lr) * 64 + kx];
                #pragma unroll
                for (int n = 0; n < 4; ++n)
                    b[n] = *(const bf16x8*)&BsH[(wc * 64 + n * 16 + lr) * 64 + kx];
                #pragma unroll
                for (int m = 0; m < 4; ++m)
                    #pragma unroll
                    for (int n = 0; n < 4; ++n)
                        acc[m][n] = __builtin_amdgcn_mfma_f32_16x16x32_bf16(a[m], b[n], acc[m][n], 0, 0, 0);
            }
        }
        const int r0 = m0 + wr * 64 + (l >> 4) * 4;
        const int c0 = n0 + wc * 64 + lr;
        #pragma unroll
        for (int m = 0; m < 4; ++m)
            #pragma unroll
            for (int n = 0; n < 4; ++n)
                #pragma unroll
                for (int r = 0; r < 4; ++r) {
                    int row = r0 + m * 16 + r;
                    int col = c0 + n * 16;
                    Cv[(long)(row >> 9) * 851968 + (long)col * 512 + (row & 511)] =
                        (__bf16)acc[m][n][r];
                }
    }
}

// ---------- single-precision bf16 GEMM: C[M][N] = A[M][K] * Bt[N][K]^T ----------
template <typename CT, bool TRANSC, bool SWZ>
__global__ __launch_bounds__(256) void gemm_bt(const __bf16* __restrict__ A,
                                               const __bf16* __restrict__ Bt,
                                               CT* __restrict__ C,
                                               int K, int lda, int ldb, int ldc,
                                               long sA, long sB, long sC,
                                               float scale, int causal, int Nlim) {
    __shared__ __bf16 As[8192];
    __shared__ __bf16 Bs[8192];
    int bx = blockIdx.x, by = blockIdx.y;
    if (SWZ) {
        int f = xcd_swz(by * gridDim.x + bx, gridDim.x * gridDim.y);
        bx = f % gridDim.x; by = f / gridDim.x;
    }
    if (causal == 2) by = gridDim.y - 1 - by;   // longest K-chunks first
    const int n0 = bx * 128, m0 = by * 128;
    A  += (long)blockIdx.z * sA;
    Bt += (long)blockIdx.z * sB;
    int ksteps = K >> 6;
    if (causal == 2) { int lim = (m0 >> 6) + 2; if (lim < ksteps) ksteps = lim; }

    const int tid = threadIdx.x;
    const int w = tid >> 6, l = tid & 63;
    const int wr = w >> 1, wc = w & 1;
    const int lr = l & 15;
    const int lk8 = (l >> 4) * 8;
    const int kswz = (lr & 7) << 3;
    const int srow = l >> 3;
    const int scol = ((l & 7) ^ (l >> 3)) * 8;

    f32x4 acc[4][4];
    #pragma unroll
    for (int m = 0; m < 4; ++m)
        #pragma unroll
        for (int n = 0; n < 4; ++n) acc[m][n] = (f32x4){0.f, 0.f, 0.f, 0.f};

    for (int kt = 0; kt < ksteps; ++kt) {
        const int k0 = kt << 6;
        __syncthreads();
        #pragma unroll
        for (int it = 0; it < 4; ++it) {
            const int j = it * 4 + w;
            const int grow = j * 8 + srow;
            gl_lds16(A  + (long)(m0 + grow) * lda + k0 + scol, &As[j * 512]);
            gl_lds16(Bt + (long)(n0 + grow) * ldb + k0 + scol, &Bs[j * 512]);
        }
        __syncthreads();
        #pragma unroll
        for (int kk = 0; kk < 2; ++kk) {
            const int kx = (kk * 32 + lk8) ^ kswz;
            bf16x8 a[4], b[4];
            #pragma unroll
            for (int m = 0; m < 4; ++m)
                a[m] = *(const bf16x8*)&As[(wr * 64 + m * 16 + lr) * 64 + kx];
            #pragma unroll
            for (int n = 0; n < 4; ++n)
                b[n] = *(const bf16x8*)&Bs[(wc * 64 + n * 16 + lr) * 64 + kx];
            #pragma unroll
            for (int m = 0; m < 4; ++m)
                #pragma unroll
                for (int n = 0; n < 4; ++n)
                    acc[m][n] = __builtin_amdgcn_mfma_f32_16x16x32_bf16(a[m], b[n], acc[m][n], 0, 0, 0);
        }
    }

    const int r0 = m0 + wr * 64 + (l >> 4) * 4;
    const int c0 = n0 + wc * 64 + lr;
    #pragma unroll
    for (int m = 0; m < 4; ++m)
        #pragma unroll
        for (int n = 0; n < 4; ++n)
            #pragma unroll
            for (int r = 0; r < 4; ++r) {
                float v = acc[m][n][r] * scale;
                int row = r0 + m * 16 + r;
                int col = c0 + n * 16;
                if (TRANSC) {
                    C[(long)(row >> 9) * sC + (long)col * ldc + (row & 511)] = (CT)v;
                } else if (col < Nlim) {
                    C[(long)blockIdx.z * sC + (long)row * ldc + col] = (CT)v;
                }
            }
}

// ---------- causal softmax: scores f32 [.][512] -> P bf16 ----------
__global__ __launch_bounds__(256) void softmax_causal(const float* __restrict__ S,
                                                      __bf16* __restrict__ P) {
    __shared__ float red[8];
    const long rid = blockIdx.x;
    const int s = (int)(rid & 511);
    const float* row = S + rid * 512;
    __bf16* prow = P + rid * 512;
    const int t = threadIdx.x;
    float x0 = (t       <= s) ? row[t]       : -3.0e38f;
    float x1 = (t + 256 <= s) ? row[t + 256] : -3.0e38f;
    float m = fmaxf(x0, x1);
    #pragma unroll
    for (int off = 1; off < 64; off <<= 1) m = fmaxf(m, __shfl_xor(m, off));
    const int w = t >> 6;
    if ((t & 63) == 0) red[w] = m;
    __syncthreads();
    m = fmaxf(fmaxf(red[0], red[1]), fmaxf(red[2], red[3]));
    float e0 = __expf(x0 - m), e1 = __expf(x1 - m);
    float sum = e0 + e1;
    #pragma unroll
    for (int off = 1; off < 64; off <<= 1) sum += __shfl_xor(sum, off);
    if ((t & 63) == 0) red[4 + w] = sum;
    __syncthreads();
    sum = red[4] + red[5] + red[6] + red[7];
    const float rinv = 1.0f / sum;
    prow[t]       = (__bf16)(e0 * rinv);
    prow[t + 256] = (__bf16)(e1 * rinv);
}

extern "C" void kernel_launch(void* const* d_in, const int* in_sizes, int n_in,
                              void* d_out, int out_size, void* d_ws, size_t ws_size,
                              hipStream_t stream) {
    (void)in_sizes; (void)n_in; (void)out_size; (void)ws_size;
    const float* x  = (const float*)d_in[0];
    const float* Wq = (const float*)d_in[1];
    const float* Wk = (const float*)d_in[2];
    const float* Wv = (const float*)d_in[3];
    const float* Wb = (const float*)d_in[4];
    float* out = (float*)d_out;
    char* ws = (char*)d_ws;

    // ---- workspace layout (bytes), peak 102,842,368 (< 108.9 MB proven) ----
    __bf16* Wqh = (__bf16*)(ws + 0);          // [1600][6400]  20,480,000
    __bf16* Wql = (__bf16*)(ws + 20480000);
    __bf16* Wkh = (__bf16*)(ws + 40960000);
    __bf16* Wkl = (__bf16*)(ws + 61440000);
    float*  Gt  = (float*) (ws + 81920000);   // [1600][1600]  10,240,000
    __bf16* Gth = (__bf16*)(ws + 92160000);   // [1664][1600]   5,324,800 (zero-padded)
    __bf16* Gtl = (__bf16*)(ws + 97484800);   // [1664][1600]   5,324,800 (zero-padded)
    __bf16* Wbt = (__bf16*)(ws + 102809600);  // [64][256]         32,768
    // phase 2 (over dead W splits; W dead after Gt GEMM):
    __bf16* xh   = (__bf16*)(ws + 0);         // [4096][1600]  13,107,200
    __bf16* xl   = (__bf16*)(ws + 13107200);
    __bf16* th   = (__bf16*)(ws + 26214400);  // [4096][1600]
    __bf16* tl   = (__bf16*)(ws + 39321600);
    __bf16* VWt  = (__bf16*)(ws + 52428800);  // [8][1664][512]13,631,488 (over Wkh/Wkl, dead)
    __bf16* WvbT = (__bf16*)(ws + 66060288);  // [1664][1600]   5,324,800 (over Wkl, dead)
    float*  s    = (float*) (ws + 81920000);  // [8][512][512]  8,388,608 (over Gt, dead)
    __bf16* P    = (__bf16*)(ws + 90308608);  // [8][512][512]  4,194,304 (over Gth, dead by softmax)
    float*  CtxF = (float*) (ws + 0);         // [8][512][1600]26,214,400 (over xh/xl, dead by PV)

    // --- Gt = Wk . Wq^T : 256^2 8-wave fused 3-pass, K-split x5 = 245 blocks (~0.96 fill) ---
    split2_f32<<<20000, 256, 0, stream>>>(Wq, Wk, Wqh, Wql, Wkh, Wkl, 10240000L);
    hipMemsetAsync(Gt, 0, 10240000, stream);
    gemm3w<true><<<dim3(7, 7, 5), 512, 0, stream>>>(
        Wkh, Wkl, Wqh, Wql, Gt,
        100, 5, 6400, 6400, 1600, 1600, 1600, 1.0f);
    hipMemsetAsync((char*)Gth + 5120000, 0, 204800, stream);
    hipMemsetAsync((char*)Gtl + 5120000, 0, 204800, stream);
    split_f32<<<2500, 256, 0, stream>>>(Gt, Gth, Gtl, 2560000L);

    // --- x split; WvbT = (Wv . blockdiag(Wb))^T (over dead Wk regions) ---
    split_f32<<<6400, 256, 0, stream>>>(x, xh, xl, 6553600L);
    cvt_wb<<<64, 256, 0, stream>>>(Wb, Wbt);
    hipMemsetAsync((char*)WvbT + 5120000, 0, 204800, stream);   // zero-pad rows 1600..1663
    wvb_kernel<<<dim3(25, 25), 256, 0, stream>>>(Wv, Wbt, WvbT);

    // --- fused dispatch: z=0 -> t = x.Gt^T (3-pass, split out), z=1 -> VWt = x.Wvb (TRANSC) ---
    gemm3m<true><<<dim3(13, 32, 2), 256, 0, stream>>>(
        xh, xl, Gth, Gtl, WvbT, th, tl, VWt);

    // --- s = 0.125 * t . x^T per batch (causal tile-skip, K-split x5, atomic) ---
    hipMemsetAsync(s, 0, 8388608, stream);
    gemm3f<1, true, false><<<dim3(4, 4, 40), 256, 0, stream>>>(
        th, tl, xh, xl, s, nullptr, nullptr,
        25, 5, 1600, 1600, 512, 512, 512, 819200L, 819200L, 262144L, 0.125f);

    softmax_causal<<<4096, 256, 0, stream>>>(s, P);

    // --- CtxF = P . VWt^T per batch : M=512, N=1664 (masked to 1600), causal k-limit ---
    gemm_bt<float, false, false><<<dim3(13, 4, 8), 256, 0, stream>>>(
        P, VWt, CtxF, 512, 512, 512, 1600,
        262144L, 851968L, 819200L, 1.0f, 2, 1600);

    // full unconditional d_out write from the staging buffer
    copy_f32<<<6400, 256, 0, stream>>>(CtxF, out);
}

// Round 14
// 345.390 us; speedup vs baseline: 1.0826x; 1.0826x over previous
//
#include <hip/hip_runtime.h>

typedef float  f32x4  __attribute__((ext_vector_type(4)));
typedef __bf16 bf16x8 __attribute__((ext_vector_type(8)));
typedef __bf16 bf16x4 __attribute__((ext_vector_type(4)));

// ---------- async global->LDS, 16B per lane ----------
__device__ __forceinline__ void gl_lds16(const void* g, void* l) {
    __builtin_amdgcn_global_load_lds(
        (const __attribute__((address_space(1))) void*)g,
        (__attribute__((address_space(3))) void*)l, 16, 0, 0);
}

// bijective XCD-aware remap (m204)
__device__ __forceinline__ int xcd_swz(int wg, int nwg) {
    int xcd = wg & 7, idx = wg >> 3;
    int q = nwg >> 3, r = nwg & 7;
    return (xcd < r ? xcd * (q + 1) : r * (q + 1) + (xcd - r) * q) + idx;
}

// ---------- split f32 -> bf16 hi + bf16 lo ----------
__global__ void split_f32(const float* __restrict__ in, __bf16* __restrict__ hi,
                          __bf16* __restrict__ lo, long n) {
    long i = ((long)blockIdx.x * blockDim.x + threadIdx.x) * 4;
    if (i >= n) return;
    float4 v = *(const float4*)&in[i];
    bf16x4 h, l;
    h[0] = (__bf16)v.x; l[0] = (__bf16)(v.x - (float)h[0]);
    h[1] = (__bf16)v.y; l[1] = (__bf16)(v.y - (float)h[1]);
    h[2] = (__bf16)v.z; l[2] = (__bf16)(v.z - (float)h[2]);
    h[3] = (__bf16)v.w; l[3] = (__bf16)(v.w - (float)h[3]);
    *(bf16x4*)&hi[i] = h;
    *(bf16x4*)&lo[i] = l;
}

// ---------- fused double split: blocks [0,half) handle A, [half,2*half) handle B ----------
__global__ void split2_f32(const float* __restrict__ a, const float* __restrict__ b,
                           __bf16* __restrict__ ah, __bf16* __restrict__ al,
                           __bf16* __restrict__ bh, __bf16* __restrict__ bl, long n) {
    long i = ((long)blockIdx.x * blockDim.x + threadIdx.x) * 4;
    const float* src = a;
    __bf16 *dh = ah, *dl = al;
    if (i >= n) { i -= n; src = b; dh = bh; dl = bl; }
    if (i >= n) return;
    float4 v = *(const float4*)&src[i];
    bf16x4 h, l;
    h[0] = (__bf16)v.x; l[0] = (__bf16)(v.x - (float)h[0]);
    h[1] = (__bf16)v.y; l[1] = (__bf16)(v.y - (float)h[1]);
    h[2] = (__bf16)v.z; l[2] = (__bf16)(v.z - (float)h[2]);
    h[3] = (__bf16)v.w; l[3] = (__bf16)(v.w - (float)h[3]);
    *(bf16x4*)&dh[i] = h;
    *(bf16x4*)&dl[i] = l;
}

// ---------- f32 -> f32 copy (full, unconditional) ----------
__global__ void copy_f32(const float* __restrict__ in, float* __restrict__ out) {
    long i = ((long)blockIdx.x * blockDim.x + threadIdx.x) * 4;
    *(float4*)&out[i] = *(const float4*)&in[i];
}

// Wb [256][64] f32 -> Wbt [64][256] bf16
__global__ void cvt_wb(const float* __restrict__ Wb, __bf16* __restrict__ Wbt) {
    int idx = blockIdx.x * 256 + threadIdx.x;
    int k = idx >> 6, n = idx & 63;
    Wbt[n * 256 + k] = (__bf16)Wb[idx];
}

// ---------- WvbT[j*64+d][k] = sum_e Wv[k][j*256+e] * Wbt[d][e]  (reads f32 Wv directly) ----------
__global__ __launch_bounds__(256) void wvb_kernel(const float* __restrict__ Wv,
                                                  const __bf16* __restrict__ Wbt,
                                                  __bf16* __restrict__ WvbT) {
    const int kb = blockIdx.x;   // 0..24
    const int j  = blockIdx.y;   // 0..24
    const int tid = threadIdx.x;
    const int w = tid >> 6, l = tid & 63;
    const long r0 = (long)kb * 64 + w * 16;
    const int lr = l & 15, lk8 = (l >> 4) * 8;
    f32x4 acc[4];
    #pragma unroll
    for (int n = 0; n < 4; ++n) acc[n] = (f32x4){0.f, 0.f, 0.f, 0.f};
    #pragma unroll
    for (int kt = 0; kt < 8; ++kt) {
        const int k = kt * 32 + lk8;
        const float* ap = &Wv[(r0 + lr) * 6400 + j * 256 + k];
        float4 f0 = *(const float4*)ap;
        float4 f1 = *(const float4*)(ap + 4);
        bf16x8 a = {(__bf16)f0.x, (__bf16)f0.y, (__bf16)f0.z, (__bf16)f0.w,
                    (__bf16)f1.x, (__bf16)f1.y, (__bf16)f1.z, (__bf16)f1.w};
        #pragma unroll
        for (int n = 0; n < 4; ++n) {
            bf16x8 b = *(const bf16x8*)&Wbt[(n * 16 + lr) * 256 + k];
            acc[n] = __builtin_amdgcn_mfma_f32_16x16x32_bf16(a, b, acc[n], 0, 0, 0);
        }
    }
    const int rr = (l >> 4) * 4;
    #pragma unroll
    for (int n = 0; n < 4; ++n)
        #pragma unroll
        for (int r = 0; r < 4; ++r)
            WvbT[(long)(j * 64 + n * 16 + lr) * 1600 + r0 + rr + r] = (__bf16)acc[n][r];
}

// ---------- fused split-precision GEMM (single-buffer, 3 passes staged once) ----------
// OUTMODE: 0 = f32 store, 1 = f32 atomic-accumulate, 2 = bf16 hi/lo split store
template <int OUTMODE, bool CAUSAL, bool SWZ>
__global__ __launch_bounds__(256) void gemm3f(
    const __bf16* __restrict__ Ahi, const __bf16* __restrict__ Alo,
    const __bf16* __restrict__ Bhi, const __bf16* __restrict__ Blo,
    float* __restrict__ C, __bf16* __restrict__ Ch, __bf16* __restrict__ Cl,
    int ktot, int nkc, int lda, int ldb, int ldc, int M, int N,
    long sA, long sB, long sC, float scale)
{
    __shared__ __bf16 AsH[8192], AsL[8192], BsH[8192], BsL[8192];  // 64 KB
    int bx = blockIdx.x, by = blockIdx.y;
    if (SWZ) {
        int f = xcd_swz(by * gridDim.x + bx, gridDim.x * gridDim.y);
        bx = f % gridDim.x; by = f / gridDim.x;
    }
    const int n0 = bx * 128, m0 = by * 128;
    if (CAUSAL && n0 > m0) return;
    const int bz = blockIdx.z;
    const int batch = bz / nkc, kc = bz % nkc;
    Ahi += (long)batch * sA; Alo += (long)batch * sA;
    Bhi += (long)batch * sB; Blo += (long)batch * sB;
    const int kbeg = (kc * ktot) / nkc;
    const int kend = ((kc + 1) * ktot) / nkc;

    const int tid = threadIdx.x;
    const int w = tid >> 6, l = tid & 63;
    const int wr = w >> 1, wc = w & 1;
    const int lr = l & 15;
    const int lk8 = (l >> 4) * 8;
    const int kswz = (lr & 7) << 3;
    const int srow = l >> 3;
    const int scol = ((l & 7) ^ (l >> 3)) * 8;   // pre-swizzled source col

    f32x4 acc[4][4];
    #pragma unroll
    for (int m = 0; m < 4; ++m)
        #pragma unroll
        for (int n = 0; n < 4; ++n) acc[m][n] = (f32x4){0.f, 0.f, 0.f, 0.f};

    for (int kt = kbeg; kt < kend; ++kt) {
        const int k0 = kt << 6;
        __syncthreads();
        #pragma unroll
        for (int it = 0; it < 4; ++it) {
            const int j = it * 4 + w;
            const int grow = j * 8 + srow;
            const long ga = (long)(m0 + grow) * lda + k0 + scol;
            const long gb = (long)(n0 + grow) * ldb + k0 + scol;
            gl_lds16(Ahi + ga, &AsH[j * 512]);
            gl_lds16(Alo + ga, &AsL[j * 512]);
            gl_lds16(Bhi + gb, &BsH[j * 512]);
            gl_lds16(Blo + gb, &BsL[j * 512]);
        }
        __syncthreads();
        #pragma unroll
        for (int kk = 0; kk < 2; ++kk) {
            const int kx = (kk * 32 + lk8) ^ kswz;
            bf16x8 ah[4], bh[4], tt[4];
            #pragma unroll
            for (int m = 0; m < 4; ++m)
                ah[m] = *(const bf16x8*)&AsH[(wr * 64 + m * 16 + lr) * 64 + kx];
            #pragma unroll
            for (int n = 0; n < 4; ++n)
                bh[n] = *(const bf16x8*)&BsH[(wc * 64 + n * 16 + lr) * 64 + kx];
            #pragma unroll
            for (int m = 0; m < 4; ++m)
                #pragma unroll
                for (int n = 0; n < 4; ++n)
                    acc[m][n] = __builtin_amdgcn_mfma_f32_16x16x32_bf16(ah[m], bh[n], acc[m][n], 0, 0, 0);
            #pragma unroll
            for (int n = 0; n < 4; ++n)
                tt[n] = *(const bf16x8*)&BsL[(wc * 64 + n * 16 + lr) * 64 + kx];
            #pragma unroll
            for (int m = 0; m < 4; ++m)
                #pragma unroll
                for (int n = 0; n < 4; ++n)
                    acc[m][n] = __builtin_amdgcn_mfma_f32_16x16x32_bf16(ah[m], tt[n], acc[m][n], 0, 0, 0);
            #pragma unroll
            for (int m = 0; m < 4; ++m)
                tt[m] = *(const bf16x8*)&AsL[(wr * 64 + m * 16 + lr) * 64 + kx];
            #pragma unroll
            for (int m = 0; m < 4; ++m)
                #pragma unroll
                for (int n = 0; n < 4; ++n)
                    acc[m][n] = __builtin_amdgcn_mfma_f32_16x16x32_bf16(tt[m], bh[n], acc[m][n], 0, 0, 0);
        }
    }

    const int r0 = wr * 64 + (l >> 4) * 4;
    const int c0 = wc * 64 + lr;
    #pragma unroll
    for (int m = 0; m < 4; ++m)
        #pragma unroll
        for (int n = 0; n < 4; ++n)
            #pragma unroll
            for (int r = 0; r < 4; ++r) {
                int row = m0 + r0 + m * 16 + r;
                int col = n0 + c0 + n * 16;
                if (row < M && col < N) {
                    float v = acc[m][n][r] * scale;
                    long idx = (long)batch * sC + (long)row * ldc + col;
                    if (OUTMODE == 1) {
                        unsafeAtomicAdd(&C[idx], v);
                    } else if (OUTMODE == 2) {
                        __bf16 h = (__bf16)v;
                        Ch[idx] = h;
                        Cl[idx] = (__bf16)(v - (float)h);
                    } else {
                        C[idx] = v;
                    }
                }
            }
}

// ---------- fused t-GEMM + VW-GEMM, one dispatch (z=0: t 3-pass, z=1: VW 1-pass) ----------
template <bool SWZ>
__global__ __launch_bounds__(256) void gemm3m(
    const __bf16* __restrict__ Ahi, const __bf16* __restrict__ Alo,
    const __bf16* __restrict__ B1h, const __bf16* __restrict__ B1l,
    const __bf16* __restrict__ B2,
    __bf16* __restrict__ Ch, __bf16* __restrict__ Cl,
    __bf16* __restrict__ Cv)
{
    __shared__ __bf16 AsH[8192], AsL[8192], BsH[8192], BsL[8192];
    int bx = blockIdx.x, by = blockIdx.y;
    if (SWZ) {
        int f = xcd_swz(by * gridDim.x + bx, gridDim.x * gridDim.y);
        bx = f % gridDim.x; by = f / gridDim.x;
    }
    const int n0 = bx * 128, m0 = by * 128;
    const int tid = threadIdx.x;
    const int w = tid >> 6, l = tid & 63;
    const int wr = w >> 1, wc = w & 1;
    const int lr = l & 15;
    const int lk8 = (l >> 4) * 8;
    const int kswz = (lr & 7) << 3;
    const int srow = l >> 3;
    const int scol = ((l & 7) ^ (l >> 3)) * 8;

    f32x4 acc[4][4];
    #pragma unroll
    for (int m = 0; m < 4; ++m)
        #pragma unroll
        for (int n = 0; n < 4; ++n) acc[m][n] = (f32x4){0.f, 0.f, 0.f, 0.f};

    if (blockIdx.z == 0) {
        for (int kt = 0; kt < 25; ++kt) {
            const int k0 = kt << 6;
            __syncthreads();
            #pragma unroll
            for (int it = 0; it < 4; ++it) {
                const int j = it * 4 + w;
                const int grow = j * 8 + srow;
                const long ga = (long)(m0 + grow) * 1600 + k0 + scol;
                const long gb = (long)(n0 + grow) * 1600 + k0 + scol;
                gl_lds16(Ahi + ga, &AsH[j * 512]);
                gl_lds16(Alo + ga, &AsL[j * 512]);
                gl_lds16(B1h + gb, &BsH[j * 512]);
                gl_lds16(B1l + gb, &BsL[j * 512]);
            }
            __syncthreads();
            #pragma unroll
            for (int kk = 0; kk < 2; ++kk) {
                const int kx = (kk * 32 + lk8) ^ kswz;
                bf16x8 ah[4], bh[4], tt[4];
                #pragma unroll
                for (int m = 0; m < 4; ++m)
                    ah[m] = *(const bf16x8*)&AsH[(wr * 64 + m * 16 + lr) * 64 + kx];
                #pragma unroll
                for (int n = 0; n < 4; ++n)
                    bh[n] = *(const bf16x8*)&BsH[(wc * 64 + n * 16 + lr) * 64 + kx];
                #pragma unroll
                for (int m = 0; m < 4; ++m)
                    #pragma unroll
                    for (int n = 0; n < 4; ++n)
                        acc[m][n] = __builtin_amdgcn_mfma_f32_16x16x32_bf16(ah[m], bh[n], acc[m][n], 0, 0, 0);
                #pragma unroll
                for (int n = 0; n < 4; ++n)
                    tt[n] = *(const bf16x8*)&BsL[(wc * 64 + n * 16 + lr) * 64 + kx];
                #pragma unroll
                for (int m = 0; m < 4; ++m)
                    #pragma unroll
                    for (int n = 0; n < 4; ++n)
                        acc[m][n] = __builtin_amdgcn_mfma_f32_16x16x32_bf16(ah[m], tt[n], acc[m][n], 0, 0, 0);
                #pragma unroll
                for (int m = 0; m < 4; ++m)
                    tt[m] = *(const bf16x8*)&AsL[(wr * 64 + m * 16 + lr) * 64 + kx];
                #pragma unroll
                for (int m = 0; m < 4; ++m)
                    #pragma unroll
                    for (int n = 0; n < 4; ++n)
                        acc[m][n] = __builtin_amdgcn_mfma_f32_16x16x32_bf16(tt[m], bh[n], acc[m][n], 0, 0, 0);
            }
        }
        const int r0 = wr * 64 + (l >> 4) * 4;
        const int c0 = wc * 64 + lr;
        #pragma unroll
        for (int m = 0; m < 4; ++m)
            #pragma unroll
            for (int n = 0; n < 4; ++n)
                #pragma unroll
                for (int r = 0; r < 4; ++r) {
                    int row = m0 + r0 + m * 16 + r;
                    int col = n0 + c0 + n * 16;
                    if (col < 1600) {
                        float v = acc[m][n][r];
                        long idx = (long)row * 1600 + col;
                        __bf16 h = (__bf16)v;
                        Ch[idx] = h;
                        Cl[idx] = (__bf16)(v - (float)h);
                    }
                }
    } else {
        for (int kt = 0; kt < 25; ++kt) {
            const int k0 = kt << 6;
            __syncthreads();
            #pragma unroll
            for (int it = 0; it < 4; ++it) {
                const int j = it * 4 + w;
                const int grow = j * 8 + srow;
                gl_lds16(Ahi + (long)(m0 + grow) * 1600 + k0 + scol, &AsH[j * 512]);
                gl_lds16(B2  + (long)(n0 + grow) * 1600 + k0 + scol, &BsH[j * 512]);
            }
            __syncthreads();
            #pragma unroll
            for (int kk = 0; kk < 2; ++kk) {
                const int kx = (kk * 32 + lk8) ^ kswz;
                bf16x8 a[4], b[4];
                #pragma unroll
                for (int m = 0; m < 4; ++m)
                    a[m] = *(const bf16x8*)&AsH[(wr * 64 + m * 16 + lr) * 64 + kx];
                #pragma unroll
                for (int n = 0; n < 4; ++n)
                    b[n] = *(const bf16x8*)&BsH[(wc * 64 + n * 16 + lr) * 64 + kx];
                #pragma unroll
                for (int m = 0; m < 4; ++m)
                    #pragma unroll
                    for (int n = 0; n < 4; ++n)
                        acc[m][n] = __builtin_amdgcn_mfma_f32_16x16x32_bf16(a[m], b[n], acc[m][n], 0, 0, 0);
            }
        }
        const int r0 = m0 + wr * 64 + (l >> 4) * 4;
        const int c0 = n0 + wc * 64 + lr;
        #pragma unroll
        for (int m = 0; m < 4; ++m)
            #pragma unroll
            for (int n = 0; n < 4; ++n)
                #pragma unroll
                for (int r = 0; r < 4; ++r) {
                    int row = r0 + m * 16 + r;
                    int col = c0 + n * 16;
                    Cv[(long)(row >> 9) * 851968 + (long)col * 512 + (row & 511)] =
                        (__bf16)acc[m][n][r];
                }
    }
}

// ---------- single-precision bf16 GEMM: C[M][N] = A[M][K] * Bt[N][K]^T ----------
template <typename CT, bool TRANSC, bool SWZ>
__global__ __launch_bounds__(256) void gemm_bt(const __bf16* __restrict__ A,
                                               const __bf16* __restrict__ Bt,
                                               CT* __restrict__ C,
                                               int K, int lda, int ldb, int ldc,
                                               long sA, long sB, long sC,
                                               float scale, int causal, int Nlim) {
    __shared__ __bf16 As[8192];
    __shared__ __bf16 Bs[8192];
    int bx = blockIdx.x, by = blockIdx.y;
    if (SWZ) {
        int f = xcd_swz(by * gridDim.x + bx, gridDim.x * gridDim.y);
        bx = f % gridDim.x; by = f / gridDim.x;
    }
    if (causal == 2) by = gridDim.y - 1 - by;   // longest K-chunks first
    const int n0 = bx * 128, m0 = by * 128;
    A  += (long)blockIdx.z * sA;
    Bt += (long)blockIdx.z * sB;
    int ksteps = K >> 6;
    if (causal == 2) { int lim = (m0 >> 6) + 2; if (lim < ksteps) ksteps = lim; }

    const int tid = threadIdx.x;
    const int w = tid >> 6, l = tid & 63;
    const int wr = w >> 1, wc = w & 1;
    const int lr = l & 15;
    const int lk8 = (l >> 4) * 8;
    const int kswz = (lr & 7) << 3;
    const int srow = l >> 3;
    const int scol = ((l & 7) ^ (l >> 3)) * 8;

    f32x4 acc[4][4];
    #pragma unroll
    for (int m = 0; m < 4; ++m)
        #pragma unroll
        for (int n = 0; n < 4; ++n) acc[m][n] = (f32x4){0.f, 0.f, 0.f, 0.f};

    for (int kt = 0; kt < ksteps; ++kt) {
        const int k0 = kt << 6;
        __syncthreads();
        #pragma unroll
        for (int it = 0; it < 4; ++it) {
            const int j = it * 4 + w;
            const int grow = j * 8 + srow;
            gl_lds16(A  + (long)(m0 + grow) * lda + k0 + scol, &As[j * 512]);
            gl_lds16(Bt + (long)(n0 + grow) * ldb + k0 + scol, &Bs[j * 512]);
        }
        __syncthreads();
        #pragma unroll
        for (int kk = 0; kk < 2; ++kk) {
            const int kx = (kk * 32 + lk8) ^ kswz;
            bf16x8 a[4], b[4];
            #pragma unroll
            for (int m = 0; m < 4; ++m)
                a[m] = *(const bf16x8*)&As[(wr * 64 + m * 16 + lr) * 64 + kx];
            #pragma unroll
            for (int n = 0; n < 4; ++n)
                b[n] = *(const bf16x8*)&Bs[(wc * 64 + n * 16 + lr) * 64 + kx];
            #pragma unroll
            for (int m = 0; m < 4; ++m)
                #pragma unroll
                for (int n = 0; n < 4; ++n)
                    acc[m][n] = __builtin_amdgcn_mfma_f32_16x16x32_bf16(a[m], b[n], acc[m][n], 0, 0, 0);
        }
    }

    const int r0 = m0 + wr * 64 + (l >> 4) * 4;
    const int c0 = n0 + wc * 64 + lr;
    #pragma unroll
    for (int m = 0; m < 4; ++m)
        #pragma unroll
        for (int n = 0; n < 4; ++n)
            #pragma unroll
            for (int r = 0; r < 4; ++r) {
                float v = acc[m][n][r] * scale;
                int row = r0 + m * 16 + r;
                int col = c0 + n * 16;
                if (TRANSC) {
                    C[(long)(row >> 9) * sC + (long)col * ldc + (row & 511)] = (CT)v;
                } else if (col < Nlim) {
                    C[(long)blockIdx.z * sC + (long)row * ldc + col] = (CT)v;
                }
            }
}

// ---------- causal softmax: scores f32 [.][512] -> P bf16 ----------
__global__ __launch_bounds__(256) void softmax_causal(const float* __restrict__ S,
                                                      __bf16* __restrict__ P) {
    __shared__ float red[8];
    const long rid = blockIdx.x;
    const int s = (int)(rid & 511);
    const float* row = S + rid * 512;
    __bf16* prow = P + rid * 512;
    const int t = threadIdx.x;
    float x0 = (t       <= s) ? row[t]       : -3.0e38f;
    float x1 = (t + 256 <= s) ? row[t + 256] : -3.0e38f;
    float m = fmaxf(x0, x1);
    #pragma unroll
    for (int off = 1; off < 64; off <<= 1) m = fmaxf(m, __shfl_xor(m, off));
    const int w = t >> 6;
    if ((t & 63) == 0) red[w] = m;
    __syncthreads();
    m = fmaxf(fmaxf(red[0], red[1]), fmaxf(red[2], red[3]));
    float e0 = __expf(x0 - m), e1 = __expf(x1 - m);
    float sum = e0 + e1;
    #pragma unroll
    for (int off = 1; off < 64; off <<= 1) sum += __shfl_xor(sum, off);
    if ((t & 63) == 0) red[4 + w] = sum;
    __syncthreads();
    sum = red[4] + red[5] + red[6] + red[7];
    const float rinv = 1.0f / sum;
    prow[t]       = (__bf16)(e0 * rinv);
    prow[t + 256] = (__bf16)(e1 * rinv);
}

extern "C" void kernel_launch(void* const* d_in, const int* in_sizes, int n_in,
                              void* d_out, int out_size, void* d_ws, size_t ws_size,
                              hipStream_t stream) {
    (void)in_sizes; (void)n_in; (void)out_size; (void)ws_size;
    const float* x  = (const float*)d_in[0];
    const float* Wq = (const float*)d_in[1];
    const float* Wk = (const float*)d_in[2];
    const float* Wv = (const float*)d_in[3];
    const float* Wb = (const float*)d_in[4];
    float* out = (float*)d_out;
    char* ws = (char*)d_ws;

    // ---- workspace layout (bytes), peak 102,842,368 (< 108.9 MB proven) ----
    __bf16* Wqh = (__bf16*)(ws + 0);          // [1600][6400]  20,480,000
    __bf16* Wql = (__bf16*)(ws + 20480000);
    __bf16* Wkh = (__bf16*)(ws + 40960000);
    __bf16* Wkl = (__bf16*)(ws + 61440000);
    float*  Gt  = (float*) (ws + 81920000);   // [1600][1600]  10,240,000
    __bf16* Gth = (__bf16*)(ws + 92160000);   // [1664][1600]   5,324,800 (zero-padded)
    __bf16* Gtl = (__bf16*)(ws + 97484800);   // [1664][1600]   5,324,800 (zero-padded)
    __bf16* Wbt = (__bf16*)(ws + 102809600);  // [64][256]         32,768
    // phase 2 (over dead W splits; W dead after Gt GEMM):
    __bf16* xh   = (__bf16*)(ws + 0);         // [4096][1600]  13,107,200
    __bf16* xl   = (__bf16*)(ws + 13107200);
    __bf16* th   = (__bf16*)(ws + 26214400);  // [4096][1600]
    __bf16* tl   = (__bf16*)(ws + 39321600);
    __bf16* VWt  = (__bf16*)(ws + 52428800);  // [8][1664][512]13,631,488 (over Wkh/Wkl, dead)
    __bf16* WvbT = (__bf16*)(ws + 66060288);  // [1664][1600]   5,324,800 (over Wkl, dead)
    float*  s    = (float*) (ws + 81920000);  // [8][512][512]  8,388,608 (over Gt, dead)
    __bf16* P    = (__bf16*)(ws + 90308608);  // [8][512][512]  4,194,304 (over Gth, dead by softmax)
    float*  CtxF = (float*) (ws + 0);         // [8][512][1600]26,214,400 (over xh/xl, dead by PV)

    // --- Gt = Wk . Wq^T (split precision, fused 3-pass, K-split x3 = 507 blocks, atomic) ---
    split2_f32<<<20000, 256, 0, stream>>>(Wq, Wk, Wqh, Wql, Wkh, Wkl, 10240000L);
    hipMemsetAsync(Gt, 0, 10240000, stream);
    gemm3f<1, false, true><<<dim3(13, 13, 3), 256, 0, stream>>>(
        Wkh, Wkl, Wqh, Wql, Gt, nullptr, nullptr,
        100, 3, 6400, 6400, 1600, 1600, 1600, 0L, 0L, 0L, 1.0f);
    hipMemsetAsync((char*)Gth + 5120000, 0, 204800, stream);
    hipMemsetAsync((char*)Gtl + 5120000, 0, 204800, stream);
    split_f32<<<2500, 256, 0, stream>>>(Gt, Gth, Gtl, 2560000L);

    // --- x split; WvbT = (Wv . blockdiag(Wb))^T (over dead Wk regions) ---
    split_f32<<<6400, 256, 0, stream>>>(x, xh, xl, 6553600L);
    cvt_wb<<<64, 256, 0, stream>>>(Wb, Wbt);
    hipMemsetAsync((char*)WvbT + 5120000, 0, 204800, stream);   // zero-pad rows 1600..1663
    wvb_kernel<<<dim3(25, 25), 256, 0, stream>>>(Wv, Wbt, WvbT);

    // --- fused dispatch: z=0 -> t = x.Gt^T (3-pass, split out), z=1 -> VWt = x.Wvb (TRANSC) ---
    gemm3m<true><<<dim3(13, 32, 2), 256, 0, stream>>>(
        xh, xl, Gth, Gtl, WvbT, th, tl, VWt);

    // --- s = 0.125 * t . x^T per batch (causal tile-skip, K-split x5, atomic) ---
    hipMemsetAsync(s, 0, 8388608, stream);
    gemm3f<1, true, false><<<dim3(4, 4, 40), 256, 0, stream>>>(
        th, tl, xh, xl, s, nullptr, nullptr,
        25, 5, 1600, 1600, 512, 512, 512, 819200L, 819200L, 262144L, 0.125f);

    softmax_causal<<<4096, 256, 0, stream>>>(s, P);

    // --- CtxF = P . VWt^T per batch : M=512, N=1664 (masked to 1600), causal k-limit ---
    gemm_bt<float, false, false><<<dim3(13, 4, 8), 256, 0, stream>>>(
        P, VWt, CtxF, 512, 512, 512, 1600,
        262144L, 851968L, 819200L, 1.0f, 2, 1600);

    // full unconditional d_out write from the staging buffer
    copy_f32<<<6400, 256, 0, stream>>>(CtxF, out);
}